// Round 5
// baseline (647.952 us; speedup 1.0000x reference)
//
#include <hip/hip_runtime.h>
#include <cstddef>

#define N_NODES  100000
#define N_EDGES  600000
#define N_GRAPHS 64

__device__ __forceinline__ void atomAddF(float* p, float v) {
    // gfx950 has HW global fp32 atomic add; unsafeAtomicAdd guarantees the HW path.
    unsafeAtomicAdd(p, v);
}

// global -> LDS direct DMA, 16B per lane. Dest must be wave-uniform base;
// HW writes lane l at base + l*16. Global src address is per-lane.
typedef __attribute__((address_space(1))) void GV;
typedef __attribute__((address_space(3))) void LV;
__device__ __forceinline__ void gload16(const float* g, float* l) {
    __builtin_amdgcn_global_load_lds((GV*)g, (LV*)l, 16, 0, 0);
}

// ---------------------------------------------------------------------------
// deg[n] = in-degree (int)
__global__ __launch_bounds__(256) void deg_count(const int* __restrict__ dst,
                                                 int* __restrict__ deg) {
    int e = blockIdx.x * 256 + threadIdx.x;
    if (e < N_EDGES) atomicAdd(deg + dst[e], 1);
}

// ---------------------------------------------------------------------------
// alloc_ranges: parallel CSR range allocation (order of node ranges arbitrary;
// only per-node contiguity matters for an unordered sum).
__global__ __launch_bounds__(256)
void alloc_ranges(const int* __restrict__ deg, int* __restrict__ beg,
                  int* __restrict__ cur, int* __restrict__ counter) {
    int n = blockIdx.x * 256 + threadIdx.x;
    int d = (n < N_NODES) ? deg[n] : 0;
    int lane = threadIdx.x & 63, wid = threadIdx.x >> 6;
    int incl = d;
#pragma unroll
    for (int o = 1; o < 64; o <<= 1) {
        int v = __shfl_up(incl, o);
        if (lane >= o) incl += v;
    }
    __shared__ int wsum[4];
    __shared__ int blockBase;
    if (lane == 63) wsum[wid] = incl;
    __syncthreads();
    if (threadIdx.x == 0) {
        int tot = wsum[0] + wsum[1] + wsum[2] + wsum[3];
        blockBase = atomicAdd(counter, tot);
    }
    __syncthreads();
    int base = blockBase;
    for (int w = 0; w < wid; ++w) base += wsum[w];
    int start = base + incl - d;
    if (n < N_NODES) { beg[n] = start; cur[n] = start; }
}

// ---------------------------------------------------------------------------
// CSR fill: csr_src[cur[d]++] = src[e].  Afterwards cur[n] = END offset.
__global__ __launch_bounds__(256)
void csr_fill(const int* __restrict__ src, const int* __restrict__ dst,
              int* __restrict__ cur, int* __restrict__ csr_src) {
    int e = blockIdx.x * 256 + threadIdx.x;
    if (e >= N_EDGES) return;
    int p = atomicAdd(cur + dst[e], 1);
    csr_src[p] = src[e];
}

// ---------------------------------------------------------------------------
// GEMM1: [S1|N1][100000 x 200] = feat[100000 x 128] @ [Wself1 | Wneigh1]
// Full-row blocks: BM=80 (1250 blocks exactly), BN=200 (both S1 and N1),
// KB=32 (4 k-tiles).  256 threads, 250 active: tr=tid/50 (TM=16 rows),
// tc=tid%50 (one float4 col-chunk).  feat read ONCE (no n0 split), writes are
// full rows; m-tile = 80*400B = exactly 400 cachelines -> single writer/line.
// A staged via global_load_lds (linear dest, 16B/lane) with source pre-swizzle
// chunk k4 = k4c ^ ((r>>3)&3): wave's two row-group A-read addresses land on
// distinct banks (broadcast x lanes) -> conflict-free scalar A-reads.
// LDS = 10KB (A) + 25.6KB (B) -> 4 blocks/CU = 16 waves (50% occupancy).
__global__ __launch_bounds__(256, 4)
void gemm1(const float* __restrict__ feat, const float* __restrict__ Wself,
           const float* __restrict__ Wneigh,
           float* __restrict__ S1, float* __restrict__ N1) {
    __shared__ float As[80 * 32];    // linear; 16B unit u = r*8 + k4c
    __shared__ float Bs[32][200];
    const int tid  = threadIdx.x;
    const int m0   = blockIdx.x * 80;
    const int wave = tid >> 6;
    const int lane = tid & 63;
    const bool active = tid < 250;
    const int tr = tid / 50;         // 0..4 (rows tr*16 .. tr*16+15)
    const int tc = tid % 50;         // col chunk: cols tc*4 .. tc*4+3

    float4 acc[16];
#pragma unroll
    for (int i = 0; i < 16; ++i) acc[i] = make_float4(0.f, 0.f, 0.f, 0.f);

    for (int kt = 0; kt < 4; ++kt) {
        const int k0 = kt * 32;
        if (kt) __syncthreads();     // previous tile's reads done before overwrite

        // A tile: 640 16B-chunks (80 rows x 8 chunks).  t=0,1: all waves;
        // t=2: waves 0,1 only.  Chunk u -> LDS offset u*16B (linear).
#pragma unroll
        for (int t = 0; t < 3; ++t) {
            int u = t * 256 + wave * 64;          // wave-uniform chunk base
            if (u < 640) {
                int uu  = u + lane;
                int r   = uu >> 3;
                int k4c = uu & 7;
                int k4  = k4c ^ ((r >> 3) & 3);   // source pre-swizzle
                gload16(feat + (size_t)(m0 + r) * 128 + k0 + k4 * 4, &As[u * 4]);
            }
        }
        // B tile: 32 k x 200 cols = 1600 float4
        for (int idx = tid; idx < 1600; idx += 256) {
            int k = idx / 50, n4 = idx % 50;
            int n = n4 * 4;
            int gk = k0 + k;
            float4 v;
            if (n < 100) v = *reinterpret_cast<const float4*>(Wself + gk * 100 + n);
            else         v = *reinterpret_cast<const float4*>(Wneigh + gk * 100 + (n - 100));
            *reinterpret_cast<float4*>(&Bs[k][n]) = v;
        }
        __syncthreads();   // drains vmcnt (gload_lds) + lgkm, then barrier

        if (active) {
            const int r0 = tr * 16;
#pragma unroll 4
            for (int k = 0; k < 32; ++k) {
                const float4 b = *reinterpret_cast<const float4*>(&Bs[k][tc * 4]);
                const int k4 = k >> 2, kl = k & 3;
#pragma unroll
                for (int i = 0; i < 16; ++i) {
                    const int r  = r0 + i;
                    const int sw = (r >> 3) & 3;
                    const float a = As[r * 32 + ((k4 ^ sw) * 4) + kl];
                    acc[i].x = fmaf(a, b.x, acc[i].x);
                    acc[i].y = fmaf(a, b.y, acc[i].y);
                    acc[i].z = fmaf(a, b.z, acc[i].z);
                    acc[i].w = fmaf(a, b.w, acc[i].w);
                }
            }
        }
    }

    if (active) {
        const int n = tc * 4;
#pragma unroll
        for (int i = 0; i < 16; ++i) {
            int gr = m0 + tr * 16 + i;
            if (n < 100) *reinterpret_cast<float4*>(S1 + (size_t)gr * 100 + n) = acc[i];
            else         *reinterpret_cast<float4*>(N1 + (size_t)gr * 100 + (n - 100)) = acc[i];
        }
    }
}

// ---------------------------------------------------------------------------
// aggregate1: A1[n][c] = sum over in-edges of N1[src][c].  float4 per lane:
// 8 nodes per 256-block, 32 lanes/node (25 live).  Zero float atomics.
__global__ __launch_bounds__(256)
void aggregate1(const float* __restrict__ N1, const int* __restrict__ csr_src,
                const int* __restrict__ beg, const int* __restrict__ cur,
                float* __restrict__ A1) {
    int n  = blockIdx.x * 8 + (threadIdx.x >> 5);
    int c4 = threadIdx.x & 31;
    if (n >= N_NODES || c4 >= 25) return;
    int b = beg[n], end = cur[n];
    float4 acc = make_float4(0.f, 0.f, 0.f, 0.f);
    int j = b;
    for (; j + 1 < end; j += 2) {
        int s0 = csr_src[j], s1 = csr_src[j + 1];
        float4 v0 = *reinterpret_cast<const float4*>(N1 + (size_t)s0 * 100 + c4 * 4);
        float4 v1 = *reinterpret_cast<const float4*>(N1 + (size_t)s1 * 100 + c4 * 4);
        acc.x += v0.x + v1.x; acc.y += v0.y + v1.y;
        acc.z += v0.z + v1.z; acc.w += v0.w + v1.w;
    }
    if (j < end) {
        int s = csr_src[j];
        float4 v = *reinterpret_cast<const float4*>(N1 + (size_t)s * 100 + c4 * 4);
        acc.x += v.x; acc.y += v.y; acc.z += v.z; acc.w += v.w;
    }
    *reinterpret_cast<float4*>(A1 + (size_t)n * 100 + c4 * 4) = acc;
}

// ---------------------------------------------------------------------------
// GEMM2: h1 = relu(S1 + A1*inv_deg + b1) fused into A-tile load;
// C[100000 x 40] = h1 @ [Wself2 | Wneigh2].  BM=64, BN=64(40 live), K=100.
__global__ __launch_bounds__(256)
void gemm2(const float* __restrict__ S1, const float* __restrict__ A1,
           const int* __restrict__ deg, const float* __restrict__ b1,
           const float* __restrict__ Ws2, const float* __restrict__ Wn2,
           float* __restrict__ S2, float* __restrict__ N2) {
    __shared__ float As[64][108];   // [m][k], K=100 padded to 108 (aligned, 2-way reads)
    __shared__ float Bs[100][64];
    const int tid = threadIdx.x;
    const int m0  = blockIdx.x * 64;

    for (int idx = tid; idx < 100 * 16; idx += 256) {   // B tile
        int k = idx >> 4, n4 = idx & 15;
        int n = n4 * 4;
        float4 v = make_float4(0.f, 0.f, 0.f, 0.f);
        if (n < 20)       v = *reinterpret_cast<const float4*>(Ws2 + k * 20 + n);
        else if (n < 40)  v = *reinterpret_cast<const float4*>(Wn2 + k * 20 + (n - 20));
        *reinterpret_cast<float4*>(&Bs[k][n]) = v;
    }
    for (int idx = tid; idx < 64 * 25; idx += 256) {    // A tile (fused h1)
        int r = idx / 25, k4 = idx % 25;
        int gr = m0 + r;
        float4 h = make_float4(0.f, 0.f, 0.f, 0.f);
        if (gr < N_NODES) {
            float4 s  = *reinterpret_cast<const float4*>(S1 + (size_t)gr * 100 + k4 * 4);
            float4 a  = *reinterpret_cast<const float4*>(A1 + (size_t)gr * 100 + k4 * 4);
            float4 bb = *reinterpret_cast<const float4*>(b1 + k4 * 4);
            float inv = 1.0f / (float)max(deg[gr], 1);
            h.x = fmaxf(fmaf(a.x, inv, s.x) + bb.x, 0.f);
            h.y = fmaxf(fmaf(a.y, inv, s.y) + bb.y, 0.f);
            h.z = fmaxf(fmaf(a.z, inv, s.z) + bb.z, 0.f);
            h.w = fmaxf(fmaf(a.w, inv, s.w) + bb.w, 0.f);
        }
        *reinterpret_cast<float4*>(&As[r][k4 * 4]) = h;
    }
    __syncthreads();

    const int tr = tid >> 4, tc = tid & 15;
    float acc[4][4] = {};
#pragma unroll 4
    for (int k = 0; k < 100; ++k) {
        float a0 = As[tr * 4 + 0][k];
        float a1 = As[tr * 4 + 1][k];
        float a2 = As[tr * 4 + 2][k];
        float a3 = As[tr * 4 + 3][k];
        float4 b = *reinterpret_cast<const float4*>(&Bs[k][tc * 4]);
        acc[0][0] += a0 * b.x; acc[0][1] += a0 * b.y; acc[0][2] += a0 * b.z; acc[0][3] += a0 * b.w;
        acc[1][0] += a1 * b.x; acc[1][1] += a1 * b.y; acc[1][2] += a1 * b.z; acc[1][3] += a1 * b.w;
        acc[2][0] += a2 * b.x; acc[2][1] += a2 * b.y; acc[2][2] += a2 * b.z; acc[2][3] += a2 * b.w;
        acc[3][0] += a3 * b.x; acc[3][1] += a3 * b.y; acc[3][2] += a3 * b.z; acc[3][3] += a3 * b.w;
    }

#pragma unroll
    for (int i = 0; i < 4; ++i) {
        int gr = m0 + tr * 4 + i;
        if (gr >= N_NODES) continue;
        int n = tc * 4;
        float4 v = make_float4(acc[i][0], acc[i][1], acc[i][2], acc[i][3]);
        if (n < 20)       *reinterpret_cast<float4*>(S2 + (size_t)gr * 20 + n) = v;
        else if (n < 40)  *reinterpret_cast<float4*>(N2 + (size_t)gr * 20 + (n - 20)) = v;
    }
}

// ---------------------------------------------------------------------------
// aggregate2: A2[n][c] = sum over in-edges of N2[src][c].  float4 per lane:
// 32 nodes per 256-block, 8 lanes/node (5 live).  Zero atomics.
__global__ __launch_bounds__(256)
void aggregate2(const float* __restrict__ N2, const int* __restrict__ csr_src,
                const int* __restrict__ beg, const int* __restrict__ cur,
                float* __restrict__ A2) {
    int n  = blockIdx.x * 32 + (threadIdx.x >> 3);
    int c4 = threadIdx.x & 7;
    if (n >= N_NODES || c4 >= 5) return;
    int b = beg[n], end = cur[n];
    float4 acc = make_float4(0.f, 0.f, 0.f, 0.f);
    int j = b;
    for (; j + 1 < end; j += 2) {
        int s0 = csr_src[j], s1 = csr_src[j + 1];
        float4 v0 = *reinterpret_cast<const float4*>(N2 + (size_t)s0 * 20 + c4 * 4);
        float4 v1 = *reinterpret_cast<const float4*>(N2 + (size_t)s1 * 20 + c4 * 4);
        acc.x += v0.x + v1.x; acc.y += v0.y + v1.y;
        acc.z += v0.z + v1.z; acc.w += v0.w + v1.w;
    }
    if (j < end) {
        int s = csr_src[j];
        float4 v = *reinterpret_cast<const float4*>(N2 + (size_t)s * 20 + c4 * 4);
        acc.x += v.x; acc.y += v.y; acc.z += v.z; acc.w += v.w;
    }
    *reinterpret_cast<float4*>(A2 + (size_t)n * 20 + c4 * 4) = acc;
}

// ---------------------------------------------------------------------------
// pool: h2 = relu(S2 + A2*inv + b2); per-graph sums + counts.
// graph_ids sorted -> most waves uniform -> wave shfl-reduce, 20 atomics/wave.
__global__ __launch_bounds__(256)
void pool_kernel(const float* __restrict__ S2, const float* __restrict__ A2,
                 const int* __restrict__ deg, const float* __restrict__ b2,
                 const int* __restrict__ gids,
                 float* __restrict__ pool, float* __restrict__ cnt) {
    int n = blockIdx.x * 256 + threadIdx.x;
    float h[20];
    int g = -1;
    if (n < N_NODES) {
        g = gids[n];
        float inv = 1.0f / (float)max(deg[n], 1);
#pragma unroll
        for (int q = 0; q < 5; ++q) {
            float4 s = *reinterpret_cast<const float4*>(S2 + (size_t)n * 20 + q * 4);
            float4 a = *reinterpret_cast<const float4*>(A2 + (size_t)n * 20 + q * 4);
            float4 bb = *reinterpret_cast<const float4*>(b2 + q * 4);
            h[q * 4 + 0] = fmaxf(fmaf(a.x, inv, s.x) + bb.x, 0.f);
            h[q * 4 + 1] = fmaxf(fmaf(a.y, inv, s.y) + bb.y, 0.f);
            h[q * 4 + 2] = fmaxf(fmaf(a.z, inv, s.z) + bb.z, 0.f);
            h[q * 4 + 3] = fmaxf(fmaf(a.w, inv, s.w) + bb.w, 0.f);
        }
    } else {
#pragma unroll
        for (int c = 0; c < 20; ++c) h[c] = 0.f;
    }
    unsigned long long act = __ballot(n < N_NODES);
    int gfirst = __shfl(g, 0);
    bool uniform = __all(g == gfirst);
    if (uniform) {
        if (gfirst >= 0) {
#pragma unroll
            for (int c = 0; c < 20; ++c)
                for (int off2 = 32; off2 > 0; off2 >>= 1)
                    h[c] += __shfl_down(h[c], off2);
            if ((threadIdx.x & 63) == 0) {
                for (int c = 0; c < 20; ++c) atomAddF(&pool[gfirst * 20 + c], h[c]);
                atomAddF(&cnt[gfirst], (float)__popcll(act));
            }
        }
    } else if (n < N_NODES) {
        for (int c = 0; c < 20; ++c) atomAddF(&pool[g * 20 + c], h[c]);
        atomAddF(&cnt[g], 1.0f);
    }
}

// ---------------------------------------------------------------------------
// head: hg = pool/cnt; out = relu(hg@fc1+b1)@fc2+b2.  One block, thread per graph.
__global__ __launch_bounds__(64)
void head(const float* __restrict__ pool, const float* __restrict__ cnt,
          const float* __restrict__ fc1w, const float* __restrict__ fc1b,
          const float* __restrict__ fc2w, const float* __restrict__ fc2b,
          float* __restrict__ out) {
    int g = threadIdx.x;
    if (g >= N_GRAPHS) return;
    float inv = 1.0f / fmaxf(cnt[g], 1.0f);
    float hg[20];
    for (int c = 0; c < 20; ++c) hg[c] = pool[g * 20 + c] * inv;
    float o = fc2b[0];
    for (int j = 0; j < 10; ++j) {
        float t = fc1b[j];
        for (int c = 0; c < 20; ++c) t = fmaf(hg[c], fc1w[c * 10 + j], t);
        o = fmaf(fmaxf(t, 0.f), fc2w[j], o);
    }
    out[g] = o;
}

// ---------------------------------------------------------------------------
extern "C" void kernel_launch(void* const* d_in, const int* in_sizes, int n_in,
                              void* d_out, int out_size, void* d_ws, size_t ws_size,
                              hipStream_t stream) {
    const float* feat   = (const float*)d_in[0];
    const float* Wself1 = (const float*)d_in[1];
    const float* Wneigh1= (const float*)d_in[2];
    const float* b1     = (const float*)d_in[3];
    const float* Wself2 = (const float*)d_in[4];
    const float* Wneigh2= (const float*)d_in[5];
    const float* b2     = (const float*)d_in[6];
    const float* fc1w   = (const float*)d_in[7];
    const float* fc1b   = (const float*)d_in[8];
    const float* fc2w   = (const float*)d_in[9];
    const float* fc2b   = (const float*)d_in[10];
    const int*   src    = (const int*)d_in[11];
    const int*   dst    = (const int*)d_in[12];
    const int*   gids   = (const int*)d_in[13];
    float* ws = (float*)d_ws;

    // workspace layout (floats); N1 region recycled for S2/N2, A1 region for A2
    float* S1 = ws;                        // 10,000,000
    float* N1 = ws + 10000000;             // 10,000,000
    float* A1 = ws + 20000000;             // 10,000,000
    float* S2 = N1;                        //  2,000,000 (N1 dead after aggregate1+gemm2 reads)
    float* N2 = N1 + 2000000;              //  2,000,000
    float* A2 = A1;                        //  2,000,000 (A1 dead after gemm2)
    int*   deg  = (int*)(ws + 30000000);   //    100,000
    float* pool = ws + 30100000;           //      1,280
    float* cnt  = ws + 30101280;           //         64
    int*   ctr  = (int*)(ws + 30101344);   //          1 (range-alloc counter)
    int*   beg  = (int*)(ws + 30101360);   //    100,000 (CSR range starts)
    int*   cur  = (int*)(ws + 30201360);   //    100,000 (fill cursors -> range ends)
    int*   csr  = (int*)(ws + 30301360);   //    600,000 (CSR src indices)
    // total: 30,901,360 floats = ~117.9 MiB

    // zero deg + pool + cnt + ctr in one shot (contiguous region)
    hipMemsetAsync(deg, 0, (100000 + 1280 + 64 + 16) * sizeof(float), stream);

    deg_count<<<(N_EDGES + 255) / 256, 256, 0, stream>>>(dst, deg);
    alloc_ranges<<<(N_NODES + 255) / 256, 256, 0, stream>>>(deg, beg, cur, ctr);
    csr_fill<<<(N_EDGES + 255) / 256, 256, 0, stream>>>(src, dst, cur, csr);

    gemm1<<<N_NODES / 80, 256, 0, stream>>>(feat, Wself1, Wneigh1, S1, N1);

    aggregate1<<<(N_NODES + 7) / 8, 256, 0, stream>>>(N1, csr, beg, cur, A1);

    gemm2<<<(N_NODES + 63) / 64, 256, 0, stream>>>(S1, A1, deg, b1, Wself2, Wneigh2, S2, N2);

    aggregate2<<<(N_NODES + 31) / 32, 256, 0, stream>>>(N2, csr, beg, cur, A2);

    pool_kernel<<<(N_NODES + 255) / 256, 256, 0, stream>>>(S2, A2, deg, b2, gids, pool, cnt);

    head<<<1, 64, 0, stream>>>(pool, cnt, fc1w, fc1b, fc2w, fc2b, (float*)d_out);
}

// Round 6
// 321.310 us; speedup vs baseline: 2.0166x; 2.0166x over previous
//
#include <hip/hip_runtime.h>
#include <cstddef>

#define N_NODES  100000
#define N_EDGES  600000
#define N_GRAPHS 64

__device__ __forceinline__ void atomAddF(float* p, float v) {
    // gfx950 has HW global fp32 atomic add; unsafeAtomicAdd guarantees the HW path.
    unsafeAtomicAdd(p, v);
}

// global -> LDS direct DMA, 16B per lane. Dest must be wave-uniform base;
// HW writes lane l at base + l*16. Global src address is per-lane.
typedef __attribute__((address_space(1))) void GV;
typedef __attribute__((address_space(3))) void LV;
__device__ __forceinline__ void gload16(const float* g, float* l) {
    __builtin_amdgcn_global_load_lds((GV*)g, (LV*)l, 16, 0, 0);
}

// ---------------------------------------------------------------------------
// deg[n] = in-degree (int)
__global__ __launch_bounds__(256) void deg_count(const int* __restrict__ dst,
                                                 int* __restrict__ deg) {
    int e = blockIdx.x * 256 + threadIdx.x;
    if (e < N_EDGES) atomicAdd(deg + dst[e], 1);
}

// ---------------------------------------------------------------------------
// alloc_ranges: parallel CSR range allocation (order of node ranges arbitrary;
// only per-node contiguity matters for an unordered sum).
__global__ __launch_bounds__(256)
void alloc_ranges(const int* __restrict__ deg, int* __restrict__ beg,
                  int* __restrict__ cur, int* __restrict__ counter) {
    int n = blockIdx.x * 256 + threadIdx.x;
    int d = (n < N_NODES) ? deg[n] : 0;
    int lane = threadIdx.x & 63, wid = threadIdx.x >> 6;
    int incl = d;
#pragma unroll
    for (int o = 1; o < 64; o <<= 1) {
        int v = __shfl_up(incl, o);
        if (lane >= o) incl += v;
    }
    __shared__ int wsum[4];
    __shared__ int blockBase;
    if (lane == 63) wsum[wid] = incl;
    __syncthreads();
    if (threadIdx.x == 0) {
        int tot = wsum[0] + wsum[1] + wsum[2] + wsum[3];
        blockBase = atomicAdd(counter, tot);
    }
    __syncthreads();
    int base = blockBase;
    for (int w = 0; w < wid; ++w) base += wsum[w];
    int start = base + incl - d;
    if (n < N_NODES) { beg[n] = start; cur[n] = start; }
}

// ---------------------------------------------------------------------------
// CSR fill: csr_src[cur[d]++] = src[e].  Afterwards cur[n] = END offset.
__global__ __launch_bounds__(256)
void csr_fill(const int* __restrict__ src, const int* __restrict__ dst,
              int* __restrict__ cur, int* __restrict__ csr_src) {
    int e = blockIdx.x * 256 + threadIdx.x;
    if (e >= N_EDGES) return;
    int p = atomicAdd(cur + dst[e], 1);
    csr_src[p] = src[e];
}

// ---------------------------------------------------------------------------
// GEMM1: [S1|N1][100000 x 200] = feat[100000 x 128] @ [Wself1 | Wneigh1]
// BM=80 (1250 blocks exactly), BN=200 (full rows, feat read ONCE), KB=32.
// 256 threads, 250 active: tr=tid/25 (TM=8 rows), tcc=tid%25 (TN=8 cols).
// acc = 16 float4 = 64 VGPR; __launch_bounds__(256,4) -> 128-VGPR cap, NO
// SPILL (round-5 lesson: (256,4)+acc[16]*float4=64 regs under a 64 cap
// spilled to scratch -> 10x HBM traffic).  TN=8 halves the scalar-A-read :
// FMA issue ratio vs round 4 (1:8 instead of 1:4).
// A staged via global_load_lds (linear dest, 16B/lane), source pre-swizzle
// k4 = k4c ^ ((r>>3)&3); A-read bank = f(tr&3), <=4 distinct tr/wave, span<=3
// -> distinct banks, broadcast across lanes -> conflict-free.
// LDS = 10KB (A) + 25.6KB (B) -> 4 blocks/CU = 16 waves (50% occupancy).
__global__ __launch_bounds__(256, 4)
void gemm1(const float* __restrict__ feat, const float* __restrict__ Wself,
           const float* __restrict__ Wneigh,
           float* __restrict__ S1, float* __restrict__ N1) {
    __shared__ float As[80 * 32];    // linear; 16B unit u = r*8 + k4c
    __shared__ float Bs[32][200];
    const int tid  = threadIdx.x;
    const int m0   = blockIdx.x * 80;
    const int wave = tid >> 6;
    const int lane = tid & 63;
    const bool active = tid < 250;
    const int tr  = tid / 25;        // 0..9 (rows tr*8 .. tr*8+7)
    const int tcc = tid % 25;        // col chunk: cols tcc*8 .. tcc*8+7
    const int sw  = tr & 3;          // thread-uniform A bank swizzle

    float4 acc0[8], acc1[8];
#pragma unroll
    for (int i = 0; i < 8; ++i) {
        acc0[i] = make_float4(0.f, 0.f, 0.f, 0.f);
        acc1[i] = make_float4(0.f, 0.f, 0.f, 0.f);
    }

    for (int kt = 0; kt < 4; ++kt) {
        const int k0 = kt * 32;
        if (kt) __syncthreads();     // previous tile's reads done before overwrite

        // A tile: 640 16B-chunks (80 rows x 8 chunks); t=0,1 all waves, t=2 waves 0,1
#pragma unroll
        for (int t = 0; t < 3; ++t) {
            int u = t * 256 + wave * 64;          // wave-uniform chunk base
            if (u < 640) {
                int uu  = u + lane;
                int r   = uu >> 3;
                int k4  = (uu & 7) ^ ((r >> 3) & 3);   // source pre-swizzle
                gload16(feat + (size_t)(m0 + r) * 128 + k0 + k4 * 4, &As[u * 4]);
            }
        }
        // B tile: 32 k x 200 cols = 1600 float4
        for (int idx = tid; idx < 1600; idx += 256) {
            int k = idx / 50, n4 = idx % 50;
            int n = n4 * 4;
            int gk = k0 + k;
            float4 v;
            if (n < 100) v = *reinterpret_cast<const float4*>(Wself + gk * 100 + n);
            else         v = *reinterpret_cast<const float4*>(Wneigh + gk * 100 + (n - 100));
            *reinterpret_cast<float4*>(&Bs[k][n]) = v;
        }
        __syncthreads();   // drains vmcnt (gload_lds) + lgkm, then barrier

        if (active) {
            const int abase = tr * 8 * 32;
#pragma unroll 4
            for (int k = 0; k < 32; ++k) {
                const float4 b0 = *reinterpret_cast<const float4*>(&Bs[k][tcc * 8]);
                const float4 b1 = *reinterpret_cast<const float4*>(&Bs[k][tcc * 8 + 4]);
                const int kc = ((k >> 2) ^ sw) * 4 + (k & 3);
#pragma unroll
                for (int i = 0; i < 8; ++i) {
                    const float a = As[abase + i * 32 + kc];
                    acc0[i].x = fmaf(a, b0.x, acc0[i].x);
                    acc0[i].y = fmaf(a, b0.y, acc0[i].y);
                    acc0[i].z = fmaf(a, b0.z, acc0[i].z);
                    acc0[i].w = fmaf(a, b0.w, acc0[i].w);
                    acc1[i].x = fmaf(a, b1.x, acc1[i].x);
                    acc1[i].y = fmaf(a, b1.y, acc1[i].y);
                    acc1[i].z = fmaf(a, b1.z, acc1[i].z);
                    acc1[i].w = fmaf(a, b1.w, acc1[i].w);
                }
            }
        }
    }

    if (active) {
        const int c0 = tcc * 8;
        const int c1 = c0 + 4;
#pragma unroll
        for (int i = 0; i < 8; ++i) {
            int gr = m0 + tr * 8 + i;
            float* p0 = (c0 < 100) ? (S1 + (size_t)gr * 100 + c0)
                                   : (N1 + (size_t)gr * 100 + (c0 - 100));
            float* p1 = (c1 < 100) ? (S1 + (size_t)gr * 100 + c1)
                                   : (N1 + (size_t)gr * 100 + (c1 - 100));
            *reinterpret_cast<float4*>(p0) = acc0[i];
            *reinterpret_cast<float4*>(p1) = acc1[i];
        }
    }
}

// ---------------------------------------------------------------------------
// aggregate1: A1[n][c] = sum over in-edges of N1[src][c].  float4 per lane:
// 8 nodes per 256-block, 32 lanes/node (25 live).  Zero float atomics.
__global__ __launch_bounds__(256)
void aggregate1(const float* __restrict__ N1, const int* __restrict__ csr_src,
                const int* __restrict__ beg, const int* __restrict__ cur,
                float* __restrict__ A1) {
    int n  = blockIdx.x * 8 + (threadIdx.x >> 5);
    int c4 = threadIdx.x & 31;
    if (n >= N_NODES || c4 >= 25) return;
    int b = beg[n], end = cur[n];
    float4 acc = make_float4(0.f, 0.f, 0.f, 0.f);
    int j = b;
    for (; j + 1 < end; j += 2) {
        int s0 = csr_src[j], s1 = csr_src[j + 1];
        float4 v0 = *reinterpret_cast<const float4*>(N1 + (size_t)s0 * 100 + c4 * 4);
        float4 v1 = *reinterpret_cast<const float4*>(N1 + (size_t)s1 * 100 + c4 * 4);
        acc.x += v0.x + v1.x; acc.y += v0.y + v1.y;
        acc.z += v0.z + v1.z; acc.w += v0.w + v1.w;
    }
    if (j < end) {
        int s = csr_src[j];
        float4 v = *reinterpret_cast<const float4*>(N1 + (size_t)s * 100 + c4 * 4);
        acc.x += v.x; acc.y += v.y; acc.z += v.z; acc.w += v.w;
    }
    *reinterpret_cast<float4*>(A1 + (size_t)n * 100 + c4 * 4) = acc;
}

// ---------------------------------------------------------------------------
// GEMM2: h1 = relu(S1 + A1*inv_deg + b1) fused into A-tile load;
// C[100000 x 40] = h1 @ [Wself2 | Wneigh2].  BM=64, BN=64(40 live), K=100.
__global__ __launch_bounds__(256)
void gemm2(const float* __restrict__ S1, const float* __restrict__ A1,
           const int* __restrict__ deg, const float* __restrict__ b1,
           const float* __restrict__ Ws2, const float* __restrict__ Wn2,
           float* __restrict__ S2, float* __restrict__ N2) {
    __shared__ float As[64][108];   // [m][k], K=100 padded to 108 (aligned, 2-way reads)
    __shared__ float Bs[100][64];
    const int tid = threadIdx.x;
    const int m0  = blockIdx.x * 64;

    for (int idx = tid; idx < 100 * 16; idx += 256) {   // B tile
        int k = idx >> 4, n4 = idx & 15;
        int n = n4 * 4;
        float4 v = make_float4(0.f, 0.f, 0.f, 0.f);
        if (n < 20)       v = *reinterpret_cast<const float4*>(Ws2 + k * 20 + n);
        else if (n < 40)  v = *reinterpret_cast<const float4*>(Wn2 + k * 20 + (n - 20));
        *reinterpret_cast<float4*>(&Bs[k][n]) = v;
    }
    for (int idx = tid; idx < 64 * 25; idx += 256) {    // A tile (fused h1)
        int r = idx / 25, k4 = idx % 25;
        int gr = m0 + r;
        float4 h = make_float4(0.f, 0.f, 0.f, 0.f);
        if (gr < N_NODES) {
            float4 s  = *reinterpret_cast<const float4*>(S1 + (size_t)gr * 100 + k4 * 4);
            float4 a  = *reinterpret_cast<const float4*>(A1 + (size_t)gr * 100 + k4 * 4);
            float4 bb = *reinterpret_cast<const float4*>(b1 + k4 * 4);
            float inv = 1.0f / (float)max(deg[gr], 1);
            h.x = fmaxf(fmaf(a.x, inv, s.x) + bb.x, 0.f);
            h.y = fmaxf(fmaf(a.y, inv, s.y) + bb.y, 0.f);
            h.z = fmaxf(fmaf(a.z, inv, s.z) + bb.z, 0.f);
            h.w = fmaxf(fmaf(a.w, inv, s.w) + bb.w, 0.f);
        }
        *reinterpret_cast<float4*>(&As[r][k4 * 4]) = h;
    }
    __syncthreads();

    const int tr = tid >> 4, tc = tid & 15;
    float acc[4][4] = {};
#pragma unroll 4
    for (int k = 0; k < 100; ++k) {
        float a0 = As[tr * 4 + 0][k];
        float a1 = As[tr * 4 + 1][k];
        float a2 = As[tr * 4 + 2][k];
        float a3 = As[tr * 4 + 3][k];
        float4 b = *reinterpret_cast<const float4*>(&Bs[k][tc * 4]);
        acc[0][0] += a0 * b.x; acc[0][1] += a0 * b.y; acc[0][2] += a0 * b.z; acc[0][3] += a0 * b.w;
        acc[1][0] += a1 * b.x; acc[1][1] += a1 * b.y; acc[1][2] += a1 * b.z; acc[1][3] += a1 * b.w;
        acc[2][0] += a2 * b.x; acc[2][1] += a2 * b.y; acc[2][2] += a2 * b.z; acc[2][3] += a2 * b.w;
        acc[3][0] += a3 * b.x; acc[3][1] += a3 * b.y; acc[3][2] += a3 * b.z; acc[3][3] += a3 * b.w;
    }

#pragma unroll
    for (int i = 0; i < 4; ++i) {
        int gr = m0 + tr * 4 + i;
        if (gr >= N_NODES) continue;
        int n = tc * 4;
        float4 v = make_float4(acc[i][0], acc[i][1], acc[i][2], acc[i][3]);
        if (n < 20)       *reinterpret_cast<float4*>(S2 + (size_t)gr * 20 + n) = v;
        else if (n < 40)  *reinterpret_cast<float4*>(N2 + (size_t)gr * 20 + (n - 20)) = v;
    }
}

// ---------------------------------------------------------------------------
// aggregate2: A2[n][c] = sum over in-edges of N2[src][c].  float4 per lane:
// 32 nodes per 256-block, 8 lanes/node (5 live).  Zero atomics.
__global__ __launch_bounds__(256)
void aggregate2(const float* __restrict__ N2, const int* __restrict__ csr_src,
                const int* __restrict__ beg, const int* __restrict__ cur,
                float* __restrict__ A2) {
    int n  = blockIdx.x * 32 + (threadIdx.x >> 3);
    int c4 = threadIdx.x & 7;
    if (n >= N_NODES || c4 >= 5) return;
    int b = beg[n], end = cur[n];
    float4 acc = make_float4(0.f, 0.f, 0.f, 0.f);
    int j = b;
    for (; j + 1 < end; j += 2) {
        int s0 = csr_src[j], s1 = csr_src[j + 1];
        float4 v0 = *reinterpret_cast<const float4*>(N2 + (size_t)s0 * 20 + c4 * 4);
        float4 v1 = *reinterpret_cast<const float4*>(N2 + (size_t)s1 * 20 + c4 * 4);
        acc.x += v0.x + v1.x; acc.y += v0.y + v1.y;
        acc.z += v0.z + v1.z; acc.w += v0.w + v1.w;
    }
    if (j < end) {
        int s = csr_src[j];
        float4 v = *reinterpret_cast<const float4*>(N2 + (size_t)s * 20 + c4 * 4);
        acc.x += v.x; acc.y += v.y; acc.z += v.z; acc.w += v.w;
    }
    *reinterpret_cast<float4*>(A2 + (size_t)n * 20 + c4 * 4) = acc;
}

// ---------------------------------------------------------------------------
// pool: h2 = relu(S2 + A2*inv + b2); per-graph sums + counts.
// graph_ids sorted -> most waves uniform -> wave shfl-reduce, 20 atomics/wave.
__global__ __launch_bounds__(256)
void pool_kernel(const float* __restrict__ S2, const float* __restrict__ A2,
                 const int* __restrict__ deg, const float* __restrict__ b2,
                 const int* __restrict__ gids,
                 float* __restrict__ pool, float* __restrict__ cnt) {
    int n = blockIdx.x * 256 + threadIdx.x;
    float h[20];
    int g = -1;
    if (n < N_NODES) {
        g = gids[n];
        float inv = 1.0f / (float)max(deg[n], 1);
#pragma unroll
        for (int q = 0; q < 5; ++q) {
            float4 s = *reinterpret_cast<const float4*>(S2 + (size_t)n * 20 + q * 4);
            float4 a = *reinterpret_cast<const float4*>(A2 + (size_t)n * 20 + q * 4);
            float4 bb = *reinterpret_cast<const float4*>(b2 + q * 4);
            h[q * 4 + 0] = fmaxf(fmaf(a.x, inv, s.x) + bb.x, 0.f);
            h[q * 4 + 1] = fmaxf(fmaf(a.y, inv, s.y) + bb.y, 0.f);
            h[q * 4 + 2] = fmaxf(fmaf(a.z, inv, s.z) + bb.z, 0.f);
            h[q * 4 + 3] = fmaxf(fmaf(a.w, inv, s.w) + bb.w, 0.f);
        }
    } else {
#pragma unroll
        for (int c = 0; c < 20; ++c) h[c] = 0.f;
    }
    unsigned long long act = __ballot(n < N_NODES);
    int gfirst = __shfl(g, 0);
    bool uniform = __all(g == gfirst);
    if (uniform) {
        if (gfirst >= 0) {
#pragma unroll
            for (int c = 0; c < 20; ++c)
                for (int off2 = 32; off2 > 0; off2 >>= 1)
                    h[c] += __shfl_down(h[c], off2);
            if ((threadIdx.x & 63) == 0) {
                for (int c = 0; c < 20; ++c) atomAddF(&pool[gfirst * 20 + c], h[c]);
                atomAddF(&cnt[gfirst], (float)__popcll(act));
            }
        }
    } else if (n < N_NODES) {
        for (int c = 0; c < 20; ++c) atomAddF(&pool[g * 20 + c], h[c]);
        atomAddF(&cnt[g], 1.0f);
    }
}

// ---------------------------------------------------------------------------
// head: hg = pool/cnt; out = relu(hg@fc1+b1)@fc2+b2.  One block, thread per graph.
__global__ __launch_bounds__(64)
void head(const float* __restrict__ pool, const float* __restrict__ cnt,
          const float* __restrict__ fc1w, const float* __restrict__ fc1b,
          const float* __restrict__ fc2w, const float* __restrict__ fc2b,
          float* __restrict__ out) {
    int g = threadIdx.x;
    if (g >= N_GRAPHS) return;
    float inv = 1.0f / fmaxf(cnt[g], 1.0f);
    float hg[20];
    for (int c = 0; c < 20; ++c) hg[c] = pool[g * 20 + c] * inv;
    float o = fc2b[0];
    for (int j = 0; j < 10; ++j) {
        float t = fc1b[j];
        for (int c = 0; c < 20; ++c) t = fmaf(hg[c], fc1w[c * 10 + j], t);
        o = fmaf(fmaxf(t, 0.f), fc2w[j], o);
    }
    out[g] = o;
}

// ---------------------------------------------------------------------------
extern "C" void kernel_launch(void* const* d_in, const int* in_sizes, int n_in,
                              void* d_out, int out_size, void* d_ws, size_t ws_size,
                              hipStream_t stream) {
    const float* feat   = (const float*)d_in[0];
    const float* Wself1 = (const float*)d_in[1];
    const float* Wneigh1= (const float*)d_in[2];
    const float* b1     = (const float*)d_in[3];
    const float* Wself2 = (const float*)d_in[4];
    const float* Wneigh2= (const float*)d_in[5];
    const float* b2     = (const float*)d_in[6];
    const float* fc1w   = (const float*)d_in[7];
    const float* fc1b   = (const float*)d_in[8];
    const float* fc2w   = (const float*)d_in[9];
    const float* fc2b   = (const float*)d_in[10];
    const int*   src    = (const int*)d_in[11];
    const int*   dst    = (const int*)d_in[12];
    const int*   gids   = (const int*)d_in[13];
    float* ws = (float*)d_ws;

    // workspace layout (floats); N1 region recycled for S2/N2, A1 region for A2
    float* S1 = ws;                        // 10,000,000
    float* N1 = ws + 10000000;             // 10,000,000
    float* A1 = ws + 20000000;             // 10,000,000
    float* S2 = N1;                        //  2,000,000 (N1 dead after aggregate1+gemm2 reads)
    float* N2 = N1 + 2000000;              //  2,000,000
    float* A2 = A1;                        //  2,000,000 (A1 dead after gemm2)
    int*   deg  = (int*)(ws + 30000000);   //    100,000
    float* pool = ws + 30100000;           //      1,280
    float* cnt  = ws + 30101280;           //         64
    int*   ctr  = (int*)(ws + 30101344);   //          1 (range-alloc counter)
    int*   beg  = (int*)(ws + 30101360);   //    100,000 (CSR range starts)
    int*   cur  = (int*)(ws + 30201360);   //    100,000 (fill cursors -> range ends)
    int*   csr  = (int*)(ws + 30301360);   //    600,000 (CSR src indices)
    // total: 30,901,360 floats = ~117.9 MiB

    // zero deg + pool + cnt + ctr in one shot (contiguous region)
    hipMemsetAsync(deg, 0, (100000 + 1280 + 64 + 16) * sizeof(float), stream);

    deg_count<<<(N_EDGES + 255) / 256, 256, 0, stream>>>(dst, deg);
    alloc_ranges<<<(N_NODES + 255) / 256, 256, 0, stream>>>(deg, beg, cur, ctr);
    csr_fill<<<(N_EDGES + 255) / 256, 256, 0, stream>>>(src, dst, cur, csr);

    gemm1<<<N_NODES / 80, 256, 0, stream>>>(feat, Wself1, Wneigh1, S1, N1);

    aggregate1<<<(N_NODES + 7) / 8, 256, 0, stream>>>(N1, csr, beg, cur, A1);

    gemm2<<<(N_NODES + 63) / 64, 256, 0, stream>>>(S1, A1, deg, b1, Wself2, Wneigh2, S2, N2);

    aggregate2<<<(N_NODES + 31) / 32, 256, 0, stream>>>(N2, csr, beg, cur, A2);

    pool_kernel<<<(N_NODES + 255) / 256, 256, 0, stream>>>(S2, A2, deg, b2, gids, pool, cnt);

    head<<<1, 64, 0, stream>>>(pool, cnt, fc1w, fc1b, fc2w, fc2b, (float*)d_out);
}

// Round 7
// 303.712 us; speedup vs baseline: 2.1334x; 1.0579x over previous
//
#include <hip/hip_runtime.h>
#include <cstddef>

#define N_NODES  100000
#define N_EDGES  600000
#define N_GRAPHS 64

__device__ __forceinline__ void atomAddF(float* p, float v) {
    // gfx950 has HW global fp32 atomic add; unsafeAtomicAdd guarantees the HW path.
    unsafeAtomicAdd(p, v);
}

// global -> LDS direct DMA, 16B per lane. Dest must be wave-uniform base;
// HW writes lane l at base + l*16. Global src address is per-lane.
typedef __attribute__((address_space(1))) void GV;
typedef __attribute__((address_space(3))) void LV;
__device__ __forceinline__ void gload16(const float* g, float* l) {
    __builtin_amdgcn_global_load_lds((GV*)g, (LV*)l, 16, 0, 0);
}

// ---------------------------------------------------------------------------
// deg[n] = in-degree (int)
__global__ __launch_bounds__(256) void deg_count(const int* __restrict__ dst,
                                                 int* __restrict__ deg) {
    int e = blockIdx.x * 256 + threadIdx.x;
    if (e < N_EDGES) atomicAdd(deg + dst[e], 1);
}

// ---------------------------------------------------------------------------
// alloc_ranges: parallel CSR range allocation (order of node ranges arbitrary;
// only per-node contiguity matters for an unordered sum).
__global__ __launch_bounds__(256)
void alloc_ranges(const int* __restrict__ deg, int* __restrict__ beg,
                  int* __restrict__ cur, int* __restrict__ counter) {
    int n = blockIdx.x * 256 + threadIdx.x;
    int d = (n < N_NODES) ? deg[n] : 0;
    int lane = threadIdx.x & 63, wid = threadIdx.x >> 6;
    int incl = d;
#pragma unroll
    for (int o = 1; o < 64; o <<= 1) {
        int v = __shfl_up(incl, o);
        if (lane >= o) incl += v;
    }
    __shared__ int wsum[4];
    __shared__ int blockBase;
    if (lane == 63) wsum[wid] = incl;
    __syncthreads();
    if (threadIdx.x == 0) {
        int tot = wsum[0] + wsum[1] + wsum[2] + wsum[3];
        blockBase = atomicAdd(counter, tot);
    }
    __syncthreads();
    int base = blockBase;
    for (int w = 0; w < wid; ++w) base += wsum[w];
    int start = base + incl - d;
    if (n < N_NODES) { beg[n] = start; cur[n] = start; }
}

// ---------------------------------------------------------------------------
// CSR fill: csr_src[cur[d]++] = src[e].  Afterwards cur[n] = END offset.
__global__ __launch_bounds__(256)
void csr_fill(const int* __restrict__ src, const int* __restrict__ dst,
              int* __restrict__ cur, int* __restrict__ csr_src) {
    int e = blockIdx.x * 256 + threadIdx.x;
    if (e >= N_EDGES) return;
    int p = atomicAdd(cur + dst[e], 1);
    csr_src[p] = src[e];
}

// ---------------------------------------------------------------------------
// GEMM1: [S1|N1][100000 x 200] = feat[100000 x 128] @ [Wself1 | Wneigh1]
// BM=40 (2500 blocks, ~10/CU available), BN=200 (full rows, feat read ONCE),
// KB=16 (8 k-tiles).  256 threads, 250 active: tr=tid/25 (TM=4 rows),
// tcc=tid%25; TN=8 as the col PAIR (tcc*4, tcc*4+100) -> both B-reads are
// 16B-stride ds_read_b128: 25 addrs over all 8 bank-slots (~3-way) instead of
// round-6's 32B-stride 4-slot fold (7-way, 8.3M conflicts).
// acc = 8 float4 = 32 VGPR; __launch_bounds__(256,6) -> 85-VGPR cap, no spill
// (round-5 lesson), 6 blocks/CU by waves; LDS 15.4KB allows 10 -> occupancy
// 24 waves/CU (75%) so cross-block staggering hides the per-kt barrier drain.
// A via global_load_lds (linear dest); source pre-swizzle k4c^((r>>2)&3),
// read kc=((k>>2)^(tr&3))*4+(k&3): <=3 distinct banks/wave, broadcast -> free.
__global__ __launch_bounds__(256, 6)
void gemm1(const float* __restrict__ feat, const float* __restrict__ Wself,
           const float* __restrict__ Wneigh,
           float* __restrict__ S1, float* __restrict__ N1) {
    __shared__ float As[40 * 16];    // linear; 16B unit u = r*4 + k4c
    __shared__ float Bs[16][200];
    const int tid  = threadIdx.x;
    const int m0   = blockIdx.x * 40;
    const int wave = tid >> 6;
    const int lane = tid & 63;
    const bool active = tid < 250;
    const int tr  = tid / 25;        // 0..9 (rows tr*4 .. tr*4+3)
    const int tcc = tid % 25;        // cols tcc*4..+3 of S1 AND of N1
    const int sw  = tr & 3;

    float4 acc0[4], acc1[4];
#pragma unroll
    for (int i = 0; i < 4; ++i) {
        acc0[i] = make_float4(0.f, 0.f, 0.f, 0.f);
        acc1[i] = make_float4(0.f, 0.f, 0.f, 0.f);
    }

    for (int kt = 0; kt < 8; ++kt) {
        const int k0 = kt * 16;
        if (kt) __syncthreads();     // previous tile's reads done before overwrite

        // A tile: 160 16B-units (40 rows x 4 chunks); wave w loads units
        // w*40..w*40+39 (lanes 0..39), dest base = w*40 units (linear).
        if (lane < 40) {
            int u  = wave * 40 + lane;
            int r  = u >> 2;
            int k4 = (u & 3) ^ ((r >> 2) & 3);     // source pre-swizzle
            gload16(feat + (size_t)(m0 + r) * 128 + k0 + k4 * 4, &As[wave * 160]);
        }
        // B tile: 16 k x 200 cols = 800 float4
        for (int idx = tid; idx < 800; idx += 256) {
            int k = idx / 50, n4 = idx % 50;
            int n = n4 * 4;
            int gk = k0 + k;
            float4 v;
            if (n < 100) v = *reinterpret_cast<const float4*>(Wself + gk * 100 + n);
            else         v = *reinterpret_cast<const float4*>(Wneigh + gk * 100 + (n - 100));
            *reinterpret_cast<float4*>(&Bs[k][n]) = v;
        }
        __syncthreads();   // drains vmcnt (gload_lds) + lgkm, then barrier

        if (active) {
            const int abase = tr * 64;             // (tr*4 rows) * 16 floats
#pragma unroll 4
            for (int k = 0; k < 16; ++k) {
                const float4 b0 = *reinterpret_cast<const float4*>(&Bs[k][tcc * 4]);
                const float4 b1 = *reinterpret_cast<const float4*>(&Bs[k][100 + tcc * 4]);
                const int kc = ((k >> 2) ^ sw) * 4 + (k & 3);
#pragma unroll
                for (int i = 0; i < 4; ++i) {
                    const float a = As[abase + i * 16 + kc];
                    acc0[i].x = fmaf(a, b0.x, acc0[i].x);
                    acc0[i].y = fmaf(a, b0.y, acc0[i].y);
                    acc0[i].z = fmaf(a, b0.z, acc0[i].z);
                    acc0[i].w = fmaf(a, b0.w, acc0[i].w);
                    acc1[i].x = fmaf(a, b1.x, acc1[i].x);
                    acc1[i].y = fmaf(a, b1.y, acc1[i].y);
                    acc1[i].z = fmaf(a, b1.z, acc1[i].z);
                    acc1[i].w = fmaf(a, b1.w, acc1[i].w);
                }
            }
        }
    }

    if (active) {
        const int c = tcc * 4;
#pragma unroll
        for (int i = 0; i < 4; ++i) {
            int gr = m0 + tr * 4 + i;              // always < N_NODES (grid exact)
            *reinterpret_cast<float4*>(S1 + (size_t)gr * 100 + c) = acc0[i];
            *reinterpret_cast<float4*>(N1 + (size_t)gr * 100 + c) = acc1[i];
        }
    }
}

// ---------------------------------------------------------------------------
// aggregate1: A1[n][c] = sum over in-edges of N1[src][c].  float4 per lane:
// 8 nodes per 256-block, 32 lanes/node (25 live).  Zero float atomics.
__global__ __launch_bounds__(256)
void aggregate1(const float* __restrict__ N1, const int* __restrict__ csr_src,
                const int* __restrict__ beg, const int* __restrict__ cur,
                float* __restrict__ A1) {
    int n  = blockIdx.x * 8 + (threadIdx.x >> 5);
    int c4 = threadIdx.x & 31;
    if (n >= N_NODES || c4 >= 25) return;
    int b = beg[n], end = cur[n];
    float4 acc = make_float4(0.f, 0.f, 0.f, 0.f);
    int j = b;
    for (; j + 1 < end; j += 2) {
        int s0 = csr_src[j], s1 = csr_src[j + 1];
        float4 v0 = *reinterpret_cast<const float4*>(N1 + (size_t)s0 * 100 + c4 * 4);
        float4 v1 = *reinterpret_cast<const float4*>(N1 + (size_t)s1 * 100 + c4 * 4);
        acc.x += v0.x + v1.x; acc.y += v0.y + v1.y;
        acc.z += v0.z + v1.z; acc.w += v0.w + v1.w;
    }
    if (j < end) {
        int s = csr_src[j];
        float4 v = *reinterpret_cast<const float4*>(N1 + (size_t)s * 100 + c4 * 4);
        acc.x += v.x; acc.y += v.y; acc.z += v.z; acc.w += v.w;
    }
    *reinterpret_cast<float4*>(A1 + (size_t)n * 100 + c4 * 4) = acc;
}

// ---------------------------------------------------------------------------
// GEMM2: h1 = relu(S1 + A1*inv_deg + b1) fused into A-tile load;
// C[100000 x 40] = h1 @ [Wself2 | Wneigh2].  BM=64, BN=64(40 live), K=100.
__global__ __launch_bounds__(256)
void gemm2(const float* __restrict__ S1, const float* __restrict__ A1,
           const int* __restrict__ deg, const float* __restrict__ b1,
           const float* __restrict__ Ws2, const float* __restrict__ Wn2,
           float* __restrict__ S2, float* __restrict__ N2) {
    __shared__ float As[64][108];   // [m][k], K=100 padded to 108 (aligned, 2-way reads)
    __shared__ float Bs[100][64];
    const int tid = threadIdx.x;
    const int m0  = blockIdx.x * 64;

    for (int idx = tid; idx < 100 * 16; idx += 256) {   // B tile
        int k = idx >> 4, n4 = idx & 15;
        int n = n4 * 4;
        float4 v = make_float4(0.f, 0.f, 0.f, 0.f);
        if (n < 20)       v = *reinterpret_cast<const float4*>(Ws2 + k * 20 + n);
        else if (n < 40)  v = *reinterpret_cast<const float4*>(Wn2 + k * 20 + (n - 20));
        *reinterpret_cast<float4*>(&Bs[k][n]) = v;
    }
    for (int idx = tid; idx < 64 * 25; idx += 256) {    // A tile (fused h1)
        int r = idx / 25, k4 = idx % 25;
        int gr = m0 + r;
        float4 h = make_float4(0.f, 0.f, 0.f, 0.f);
        if (gr < N_NODES) {
            float4 s  = *reinterpret_cast<const float4*>(S1 + (size_t)gr * 100 + k4 * 4);
            float4 a  = *reinterpret_cast<const float4*>(A1 + (size_t)gr * 100 + k4 * 4);
            float4 bb = *reinterpret_cast<const float4*>(b1 + k4 * 4);
            float inv = 1.0f / (float)max(deg[gr], 1);
            h.x = fmaxf(fmaf(a.x, inv, s.x) + bb.x, 0.f);
            h.y = fmaxf(fmaf(a.y, inv, s.y) + bb.y, 0.f);
            h.z = fmaxf(fmaf(a.z, inv, s.z) + bb.z, 0.f);
            h.w = fmaxf(fmaf(a.w, inv, s.w) + bb.w, 0.f);
        }
        *reinterpret_cast<float4*>(&As[r][k4 * 4]) = h;
    }
    __syncthreads();

    const int tr = tid >> 4, tc = tid & 15;
    float acc[4][4] = {};
#pragma unroll 4
    for (int k = 0; k < 100; ++k) {
        float a0 = As[tr * 4 + 0][k];
        float a1 = As[tr * 4 + 1][k];
        float a2 = As[tr * 4 + 2][k];
        float a3 = As[tr * 4 + 3][k];
        float4 b = *reinterpret_cast<const float4*>(&Bs[k][tc * 4]);
        acc[0][0] += a0 * b.x; acc[0][1] += a0 * b.y; acc[0][2] += a0 * b.z; acc[0][3] += a0 * b.w;
        acc[1][0] += a1 * b.x; acc[1][1] += a1 * b.y; acc[1][2] += a1 * b.z; acc[1][3] += a1 * b.w;
        acc[2][0] += a2 * b.x; acc[2][1] += a2 * b.y; acc[2][2] += a2 * b.z; acc[2][3] += a2 * b.w;
        acc[3][0] += a3 * b.x; acc[3][1] += a3 * b.y; acc[3][2] += a3 * b.z; acc[3][3] += a3 * b.w;
    }

#pragma unroll
    for (int i = 0; i < 4; ++i) {
        int gr = m0 + tr * 4 + i;
        if (gr >= N_NODES) continue;
        int n = tc * 4;
        float4 v = make_float4(acc[i][0], acc[i][1], acc[i][2], acc[i][3]);
        if (n < 20)       *reinterpret_cast<float4*>(S2 + (size_t)gr * 20 + n) = v;
        else if (n < 40)  *reinterpret_cast<float4*>(N2 + (size_t)gr * 20 + (n - 20)) = v;
    }
}

// ---------------------------------------------------------------------------
// aggregate2: A2[n][c] = sum over in-edges of N2[src][c].  float4 per lane:
// 32 nodes per 256-block, 8 lanes/node (5 live).  Zero atomics.
__global__ __launch_bounds__(256)
void aggregate2(const float* __restrict__ N2, const int* __restrict__ csr_src,
                const int* __restrict__ beg, const int* __restrict__ cur,
                float* __restrict__ A2) {
    int n  = blockIdx.x * 32 + (threadIdx.x >> 3);
    int c4 = threadIdx.x & 7;
    if (n >= N_NODES || c4 >= 5) return;
    int b = beg[n], end = cur[n];
    float4 acc = make_float4(0.f, 0.f, 0.f, 0.f);
    int j = b;
    for (; j + 1 < end; j += 2) {
        int s0 = csr_src[j], s1 = csr_src[j + 1];
        float4 v0 = *reinterpret_cast<const float4*>(N2 + (size_t)s0 * 20 + c4 * 4);
        float4 v1 = *reinterpret_cast<const float4*>(N2 + (size_t)s1 * 20 + c4 * 4);
        acc.x += v0.x + v1.x; acc.y += v0.y + v1.y;
        acc.z += v0.z + v1.z; acc.w += v0.w + v1.w;
    }
    if (j < end) {
        int s = csr_src[j];
        float4 v = *reinterpret_cast<const float4*>(N2 + (size_t)s * 20 + c4 * 4);
        acc.x += v.x; acc.y += v.y; acc.z += v.z; acc.w += v.w;
    }
    *reinterpret_cast<float4*>(A2 + (size_t)n * 20 + c4 * 4) = acc;
}

// ---------------------------------------------------------------------------
// pool: h2 = relu(S2 + A2*inv + b2); per-graph sums + counts.
// graph_ids sorted -> most waves uniform -> wave shfl-reduce, 20 atomics/wave.
__global__ __launch_bounds__(256)
void pool_kernel(const float* __restrict__ S2, const float* __restrict__ A2,
                 const int* __restrict__ deg, const float* __restrict__ b2,
                 const int* __restrict__ gids,
                 float* __restrict__ pool, float* __restrict__ cnt) {
    int n = blockIdx.x * 256 + threadIdx.x;
    float h[20];
    int g = -1;
    if (n < N_NODES) {
        g = gids[n];
        float inv = 1.0f / (float)max(deg[n], 1);
#pragma unroll
        for (int q = 0; q < 5; ++q) {
            float4 s = *reinterpret_cast<const float4*>(S2 + (size_t)n * 20 + q * 4);
            float4 a = *reinterpret_cast<const float4*>(A2 + (size_t)n * 20 + q * 4);
            float4 bb = *reinterpret_cast<const float4*>(b2 + q * 4);
            h[q * 4 + 0] = fmaxf(fmaf(a.x, inv, s.x) + bb.x, 0.f);
            h[q * 4 + 1] = fmaxf(fmaf(a.y, inv, s.y) + bb.y, 0.f);
            h[q * 4 + 2] = fmaxf(fmaf(a.z, inv, s.z) + bb.z, 0.f);
            h[q * 4 + 3] = fmaxf(fmaf(a.w, inv, s.w) + bb.w, 0.f);
        }
    } else {
#pragma unroll
        for (int c = 0; c < 20; ++c) h[c] = 0.f;
    }
    unsigned long long act = __ballot(n < N_NODES);
    int gfirst = __shfl(g, 0);
    bool uniform = __all(g == gfirst);
    if (uniform) {
        if (gfirst >= 0) {
#pragma unroll
            for (int c = 0; c < 20; ++c)
                for (int off2 = 32; off2 > 0; off2 >>= 1)
                    h[c] += __shfl_down(h[c], off2);
            if ((threadIdx.x & 63) == 0) {
                for (int c = 0; c < 20; ++c) atomAddF(&pool[gfirst * 20 + c], h[c]);
                atomAddF(&cnt[gfirst], (float)__popcll(act));
            }
        }
    } else if (n < N_NODES) {
        for (int c = 0; c < 20; ++c) atomAddF(&pool[g * 20 + c], h[c]);
        atomAddF(&cnt[g], 1.0f);
    }
}

// ---------------------------------------------------------------------------
// head: hg = pool/cnt; out = relu(hg@fc1+b1)@fc2+b2.  One block, thread per graph.
__global__ __launch_bounds__(64)
void head(const float* __restrict__ pool, const float* __restrict__ cnt,
          const float* __restrict__ fc1w, const float* __restrict__ fc1b,
          const float* __restrict__ fc2w, const float* __restrict__ fc2b,
          float* __restrict__ out) {
    int g = threadIdx.x;
    if (g >= N_GRAPHS) return;
    float inv = 1.0f / fmaxf(cnt[g], 1.0f);
    float hg[20];
    for (int c = 0; c < 20; ++c) hg[c] = pool[g * 20 + c] * inv;
    float o = fc2b[0];
    for (int j = 0; j < 10; ++j) {
        float t = fc1b[j];
        for (int c = 0; c < 20; ++c) t = fmaf(hg[c], fc1w[c * 10 + j], t);
        o = fmaf(fmaxf(t, 0.f), fc2w[j], o);
    }
    out[g] = o;
}

// ---------------------------------------------------------------------------
extern "C" void kernel_launch(void* const* d_in, const int* in_sizes, int n_in,
                              void* d_out, int out_size, void* d_ws, size_t ws_size,
                              hipStream_t stream) {
    const float* feat   = (const float*)d_in[0];
    const float* Wself1 = (const float*)d_in[1];
    const float* Wneigh1= (const float*)d_in[2];
    const float* b1     = (const float*)d_in[3];
    const float* Wself2 = (const float*)d_in[4];
    const float* Wneigh2= (const float*)d_in[5];
    const float* b2     = (const float*)d_in[6];
    const float* fc1w   = (const float*)d_in[7];
    const float* fc1b   = (const float*)d_in[8];
    const float* fc2w   = (const float*)d_in[9];
    const float* fc2b   = (const float*)d_in[10];
    const int*   src    = (const int*)d_in[11];
    const int*   dst    = (const int*)d_in[12];
    const int*   gids   = (const int*)d_in[13];
    float* ws = (float*)d_ws;

    // workspace layout (floats); N1 region recycled for S2/N2, A1 region for A2
    float* S1 = ws;                        // 10,000,000
    float* N1 = ws + 10000000;             // 10,000,000
    float* A1 = ws + 20000000;             // 10,000,000
    float* S2 = N1;                        //  2,000,000 (N1 dead after aggregate1+gemm2 reads)
    float* N2 = N1 + 2000000;              //  2,000,000
    float* A2 = A1;                        //  2,000,000 (A1 dead after gemm2)
    int*   deg  = (int*)(ws + 30000000);   //    100,000
    float* pool = ws + 30100000;           //      1,280
    float* cnt  = ws + 30101280;           //         64
    int*   ctr  = (int*)(ws + 30101344);   //          1 (range-alloc counter)
    int*   beg  = (int*)(ws + 30101360);   //    100,000 (CSR range starts)
    int*   cur  = (int*)(ws + 30201360);   //    100,000 (fill cursors -> range ends)
    int*   csr  = (int*)(ws + 30301360);   //    600,000 (CSR src indices)
    // total: 30,901,360 floats = ~117.9 MiB

    // zero deg + pool + cnt + ctr in one shot (contiguous region)
    hipMemsetAsync(deg, 0, (100000 + 1280 + 64 + 16) * sizeof(float), stream);

    deg_count<<<(N_EDGES + 255) / 256, 256, 0, stream>>>(dst, deg);
    alloc_ranges<<<(N_NODES + 255) / 256, 256, 0, stream>>>(deg, beg, cur, ctr);
    csr_fill<<<(N_EDGES + 255) / 256, 256, 0, stream>>>(src, dst, cur, csr);

    gemm1<<<N_NODES / 40, 256, 0, stream>>>(feat, Wself1, Wneigh1, S1, N1);

    aggregate1<<<(N_NODES + 7) / 8, 256, 0, stream>>>(N1, csr, beg, cur, A1);

    gemm2<<<(N_NODES + 63) / 64, 256, 0, stream>>>(S1, A1, deg, b1, Wself2, Wneigh2, S2, N2);

    aggregate2<<<(N_NODES + 31) / 32, 256, 0, stream>>>(N2, csr, beg, cur, A2);

    pool_kernel<<<(N_NODES + 255) / 256, 256, 0, stream>>>(S2, A2, deg, b2, gids, pool, cnt);

    head<<<1, 64, 0, stream>>>(pool, cnt, fc1w, fc1b, fc2w, fc2b, (float*)d_out);
}

// Round 8
// 296.314 us; speedup vs baseline: 2.1867x; 1.0250x over previous
//
#include <hip/hip_runtime.h>
#include <cstddef>

#define N_NODES  100000
#define N_EDGES  600000
#define N_GRAPHS 64

__device__ __forceinline__ void atomAddF(float* p, float v) {
    // gfx950 has HW global fp32 atomic add; unsafeAtomicAdd guarantees the HW path.
    unsafeAtomicAdd(p, v);
}

// compile-time float4 element select (folds to member access when i is literal)
__device__ __forceinline__ float f4get(const float4& v, int i) {
    return i == 0 ? v.x : i == 1 ? v.y : i == 2 ? v.z : v.w;
}

// global -> LDS direct DMA, 16B per lane. Dest must be wave-uniform base;
// HW writes lane l at base + l*16. Global src address is per-lane.
typedef __attribute__((address_space(1))) void GV;
typedef __attribute__((address_space(3))) void LV;
__device__ __forceinline__ void gload16(const float* g, float* l) {
    __builtin_amdgcn_global_load_lds((GV*)g, (LV*)l, 16, 0, 0);
}

// ---------------------------------------------------------------------------
// deg[n] = in-degree (int)
__global__ __launch_bounds__(256) void deg_count(const int* __restrict__ dst,
                                                 int* __restrict__ deg) {
    int e = blockIdx.x * 256 + threadIdx.x;
    if (e < N_EDGES) atomicAdd(deg + dst[e], 1);
}

// ---------------------------------------------------------------------------
// alloc_ranges: parallel CSR range allocation (order of node ranges arbitrary;
// only per-node contiguity matters for an unordered sum).
__global__ __launch_bounds__(256)
void alloc_ranges(const int* __restrict__ deg, int* __restrict__ beg,
                  int* __restrict__ cur, int* __restrict__ counter) {
    int n = blockIdx.x * 256 + threadIdx.x;
    int d = (n < N_NODES) ? deg[n] : 0;
    int lane = threadIdx.x & 63, wid = threadIdx.x >> 6;
    int incl = d;
#pragma unroll
    for (int o = 1; o < 64; o <<= 1) {
        int v = __shfl_up(incl, o);
        if (lane >= o) incl += v;
    }
    __shared__ int wsum[4];
    __shared__ int blockBase;
    if (lane == 63) wsum[wid] = incl;
    __syncthreads();
    if (threadIdx.x == 0) {
        int tot = wsum[0] + wsum[1] + wsum[2] + wsum[3];
        blockBase = atomicAdd(counter, tot);
    }
    __syncthreads();
    int base = blockBase;
    for (int w = 0; w < wid; ++w) base += wsum[w];
    int start = base + incl - d;
    if (n < N_NODES) { beg[n] = start; cur[n] = start; }
}

// ---------------------------------------------------------------------------
// CSR fill: csr_src[cur[d]++] = src[e].  Afterwards cur[n] = END offset.
__global__ __launch_bounds__(256)
void csr_fill(const int* __restrict__ src, const int* __restrict__ dst,
              int* __restrict__ cur, int* __restrict__ csr_src) {
    int e = blockIdx.x * 256 + threadIdx.x;
    if (e >= N_EDGES) return;
    int p = atomicAdd(cur + dst[e], 1);
    csr_src[p] = src[e];
}

// ---------------------------------------------------------------------------
// GEMM1: [S1|N1][100000 x 200] = feat[100000 x 128] @ [Wself1 | Wneigh1]
// BM=40, BN=200 (feat read once), KB=16.  250 active threads: tr=tid/25
// (TM=4 rows), tcc=tid%25 (col pair tcc*4 / tcc*4+100).
// A-reads VECTORIZED: float4 of 4 k per row (LDS [row][16k] linear layout from
// gload16), halving LDS issue count vs round 7's scalar reads.  Source
// pre-swizzle chunk k4 = k4c ^ ((r>>2)&3); read chunk = g ^ (tr&3): wave's 3
// tr-groups hit 3 distinct bank-slots, broadcast across lanes -> conflict-free.
// B-read ~3-4-way conflict is inherent (25 distinct float4 addrs over 8 slots).
// acc 32 + a 16 + b 8 regs < 85 cap (launch_bounds(256,6)) -> no spill.
__global__ __launch_bounds__(256, 6)
void gemm1(const float* __restrict__ feat, const float* __restrict__ Wself,
           const float* __restrict__ Wneigh,
           float* __restrict__ S1, float* __restrict__ N1) {
    __shared__ float As[40 * 16];    // [row][k-chunk swizzled], linear from gload
    __shared__ float Bs[16][200];
    const int tid  = threadIdx.x;
    const int m0   = blockIdx.x * 40;
    const int wave = tid >> 6;
    const int lane = tid & 63;
    const bool active = tid < 250;
    const int tr  = tid / 25;        // 0..9 (rows tr*4 .. tr*4+3)
    const int tcc = tid % 25;        // cols tcc*4..+3 of S1 AND of N1
    const int sw  = tr & 3;

    float4 acc0[4], acc1[4];
#pragma unroll
    for (int i = 0; i < 4; ++i) {
        acc0[i] = make_float4(0.f, 0.f, 0.f, 0.f);
        acc1[i] = make_float4(0.f, 0.f, 0.f, 0.f);
    }

    for (int kt = 0; kt < 8; ++kt) {
        const int k0 = kt * 16;
        if (kt) __syncthreads();     // previous tile's reads done before overwrite

        // A tile: 160 16B-units (40 rows x 4 chunks); wave w loads units
        // w*40..w*40+39 (lanes 0..39), dest base = w*40 units (linear).
        if (lane < 40) {
            int u  = wave * 40 + lane;
            int r  = u >> 2;
            int k4 = (u & 3) ^ ((r >> 2) & 3);     // source pre-swizzle
            gload16(feat + (size_t)(m0 + r) * 128 + k0 + k4 * 4, &As[wave * 160]);
        }
        // B tile: 16 k x 200 cols = 800 float4
        for (int idx = tid; idx < 800; idx += 256) {
            int k = idx / 50, n4 = idx % 50;
            int n = n4 * 4;
            int gk = k0 + k;
            float4 v;
            if (n < 100) v = *reinterpret_cast<const float4*>(Wself + gk * 100 + n);
            else         v = *reinterpret_cast<const float4*>(Wneigh + gk * 100 + (n - 100));
            *reinterpret_cast<float4*>(&Bs[k][n]) = v;
        }
        __syncthreads();   // drains vmcnt (gload_lds) + lgkm, then barrier

        if (active) {
            const int abase = tr * 64;             // (tr*4 rows) * 16 floats
#pragma unroll
            for (int g = 0; g < 4; ++g) {
                const int ac = ((g ^ sw) << 2);    // swizzled chunk offset
                const float4 a0 = *reinterpret_cast<const float4*>(&As[abase +  0 + ac]);
                const float4 a1 = *reinterpret_cast<const float4*>(&As[abase + 16 + ac]);
                const float4 a2 = *reinterpret_cast<const float4*>(&As[abase + 32 + ac]);
                const float4 a3 = *reinterpret_cast<const float4*>(&As[abase + 48 + ac]);
#pragma unroll
                for (int kl = 0; kl < 4; ++kl) {
                    const int k = g * 4 + kl;
                    const float4 b0 = *reinterpret_cast<const float4*>(&Bs[k][tcc * 4]);
                    const float4 b1 = *reinterpret_cast<const float4*>(&Bs[k][100 + tcc * 4]);
                    const float v0 = f4get(a0, kl), v1 = f4get(a1, kl);
                    const float v2 = f4get(a2, kl), v3 = f4get(a3, kl);
                    acc0[0].x = fmaf(v0, b0.x, acc0[0].x); acc0[0].y = fmaf(v0, b0.y, acc0[0].y);
                    acc0[0].z = fmaf(v0, b0.z, acc0[0].z); acc0[0].w = fmaf(v0, b0.w, acc0[0].w);
                    acc1[0].x = fmaf(v0, b1.x, acc1[0].x); acc1[0].y = fmaf(v0, b1.y, acc1[0].y);
                    acc1[0].z = fmaf(v0, b1.z, acc1[0].z); acc1[0].w = fmaf(v0, b1.w, acc1[0].w);
                    acc0[1].x = fmaf(v1, b0.x, acc0[1].x); acc0[1].y = fmaf(v1, b0.y, acc0[1].y);
                    acc0[1].z = fmaf(v1, b0.z, acc0[1].z); acc0[1].w = fmaf(v1, b0.w, acc0[1].w);
                    acc1[1].x = fmaf(v1, b1.x, acc1[1].x); acc1[1].y = fmaf(v1, b1.y, acc1[1].y);
                    acc1[1].z = fmaf(v1, b1.z, acc1[1].z); acc1[1].w = fmaf(v1, b1.w, acc1[1].w);
                    acc0[2].x = fmaf(v2, b0.x, acc0[2].x); acc0[2].y = fmaf(v2, b0.y, acc0[2].y);
                    acc0[2].z = fmaf(v2, b0.z, acc0[2].z); acc0[2].w = fmaf(v2, b0.w, acc0[2].w);
                    acc1[2].x = fmaf(v2, b1.x, acc1[2].x); acc1[2].y = fmaf(v2, b1.y, acc1[2].y);
                    acc1[2].z = fmaf(v2, b1.z, acc1[2].z); acc1[2].w = fmaf(v2, b1.w, acc1[2].w);
                    acc0[3].x = fmaf(v3, b0.x, acc0[3].x); acc0[3].y = fmaf(v3, b0.y, acc0[3].y);
                    acc0[3].z = fmaf(v3, b0.z, acc0[3].z); acc0[3].w = fmaf(v3, b0.w, acc0[3].w);
                    acc1[3].x = fmaf(v3, b1.x, acc1[3].x); acc1[3].y = fmaf(v3, b1.y, acc1[3].y);
                    acc1[3].z = fmaf(v3, b1.z, acc1[3].z); acc1[3].w = fmaf(v3, b1.w, acc1[3].w);
                }
            }
        }
    }

    if (active) {
        const int c = tcc * 4;
#pragma unroll
        for (int i = 0; i < 4; ++i) {
            int gr = m0 + tr * 4 + i;              // always < N_NODES (grid exact)
            *reinterpret_cast<float4*>(S1 + (size_t)gr * 100 + c) = acc0[i];
            *reinterpret_cast<float4*>(N1 + (size_t)gr * 100 + c) = acc1[i];
        }
    }
}

// ---------------------------------------------------------------------------
// aggregate1 + fused h1 epilogue: h1[n] = relu(S1[n] + (sum N1[src])*inv + b1).
// inv from (end-beg) == deg, no deg read.  8 nodes/256-block, 32 lanes/node
// (25 live), float4 per lane.  Zero float atomics; every row written.
__global__ __launch_bounds__(256)
void aggregate1(const float* __restrict__ N1, const float* __restrict__ S1,
                const float* __restrict__ b1, const int* __restrict__ csr_src,
                const int* __restrict__ beg, const int* __restrict__ cur,
                float* __restrict__ h1) {
    int n  = blockIdx.x * 8 + (threadIdx.x >> 5);
    int c4 = threadIdx.x & 31;
    if (n >= N_NODES || c4 >= 25) return;
    int b = beg[n], end = cur[n];
    float4 acc = make_float4(0.f, 0.f, 0.f, 0.f);
    int j = b;
    for (; j + 1 < end; j += 2) {
        int s0 = csr_src[j], s1 = csr_src[j + 1];
        float4 v0 = *reinterpret_cast<const float4*>(N1 + (size_t)s0 * 100 + c4 * 4);
        float4 v1 = *reinterpret_cast<const float4*>(N1 + (size_t)s1 * 100 + c4 * 4);
        acc.x += v0.x + v1.x; acc.y += v0.y + v1.y;
        acc.z += v0.z + v1.z; acc.w += v0.w + v1.w;
    }
    if (j < end) {
        int s = csr_src[j];
        float4 v = *reinterpret_cast<const float4*>(N1 + (size_t)s * 100 + c4 * 4);
        acc.x += v.x; acc.y += v.y; acc.z += v.z; acc.w += v.w;
    }
    float inv = 1.0f / (float)max(end - b, 1);
    float4 s  = *reinterpret_cast<const float4*>(S1 + (size_t)n * 100 + c4 * 4);
    float4 bb = *reinterpret_cast<const float4*>(b1 + c4 * 4);
    float4 h;
    h.x = fmaxf(fmaf(acc.x, inv, s.x) + bb.x, 0.f);
    h.y = fmaxf(fmaf(acc.y, inv, s.y) + bb.y, 0.f);
    h.z = fmaxf(fmaf(acc.z, inv, s.z) + bb.z, 0.f);
    h.w = fmaxf(fmaf(acc.w, inv, s.w) + bb.w, 0.f);
    *reinterpret_cast<float4*>(h1 + (size_t)n * 100 + c4 * 4) = h;
}

// ---------------------------------------------------------------------------
// GEMM2: C[100000 x 40] = h1 @ [Wself2 | Wneigh2].  BM=64, K=100 (single
// tile).  A-tile is now a pure copy of h1 -> global_load_lds (no pad; scalar
// a-reads are 2-way-free).  B narrowed to live 40 cols (16KB).
__global__ __launch_bounds__(256)
void gemm2(const float* __restrict__ h1,
           const float* __restrict__ Ws2, const float* __restrict__ Wn2,
           float* __restrict__ S2, float* __restrict__ N2) {
    __shared__ float As[64 * 100];  // [r][k] linear, 25.6KB
    __shared__ float Bs[100][40];   // 16KB
    const int tid  = threadIdx.x;
    const int m0   = blockIdx.x * 64;
    const int wave = tid >> 6;
    const int lane = tid & 63;

    // A tile: 1600 16B-units via gload (linear dest)
#pragma unroll
    for (int t = 0; t < 7; ++t) {
        int u0 = t * 256 + wave * 64;
        if (u0 < 1600) {
            int u  = u0 + lane;
            int r  = u / 25, c4 = u % 25;
            int gr = m0 + r; if (gr >= N_NODES) gr = N_NODES - 1;  // tail clamp
            gload16(h1 + (size_t)gr * 100 + c4 * 4, &As[u0 * 4]);
        }
    }
    // B tile: 100 k x 10 float4
    for (int idx = tid; idx < 1000; idx += 256) {
        int k = idx / 10, n4 = idx % 10;
        int n = n4 * 4;
        float4 v;
        if (n < 20) v = *reinterpret_cast<const float4*>(Ws2 + k * 20 + n);
        else        v = *reinterpret_cast<const float4*>(Wn2 + k * 20 + (n - 20));
        *reinterpret_cast<float4*>(&Bs[k][n]) = v;
    }
    __syncthreads();

    const int tr = tid >> 4, tc = tid & 15;
    if (tc < 10) {
        float acc[4][4] = {};
#pragma unroll 4
        for (int k = 0; k < 100; ++k) {
            float a0 = As[(tr * 4 + 0) * 100 + k];
            float a1 = As[(tr * 4 + 1) * 100 + k];
            float a2 = As[(tr * 4 + 2) * 100 + k];
            float a3 = As[(tr * 4 + 3) * 100 + k];
            float4 b = *reinterpret_cast<const float4*>(&Bs[k][tc * 4]);
            acc[0][0] += a0 * b.x; acc[0][1] += a0 * b.y; acc[0][2] += a0 * b.z; acc[0][3] += a0 * b.w;
            acc[1][0] += a1 * b.x; acc[1][1] += a1 * b.y; acc[1][2] += a1 * b.z; acc[1][3] += a1 * b.w;
            acc[2][0] += a2 * b.x; acc[2][1] += a2 * b.y; acc[2][2] += a2 * b.z; acc[2][3] += a2 * b.w;
            acc[3][0] += a3 * b.x; acc[3][1] += a3 * b.y; acc[3][2] += a3 * b.z; acc[3][3] += a3 * b.w;
        }
#pragma unroll
        for (int i = 0; i < 4; ++i) {
            int gr = m0 + tr * 4 + i;
            if (gr >= N_NODES) continue;
            int n = tc * 4;
            float4 v = make_float4(acc[i][0], acc[i][1], acc[i][2], acc[i][3]);
            if (n < 20) *reinterpret_cast<float4*>(S2 + (size_t)gr * 20 + n) = v;
            else        *reinterpret_cast<float4*>(N2 + (size_t)gr * 20 + (n - 20)) = v;
        }
    }
}

// ---------------------------------------------------------------------------
// aggregate2 + fused h2 epilogue: h2 = relu(S2 + (sum N2[src])*inv + b2).
// 32 nodes per 256-block, 8 lanes/node (5 live).  Zero atomics.
__global__ __launch_bounds__(256)
void aggregate2(const float* __restrict__ N2, const float* __restrict__ S2,
                const float* __restrict__ b2, const int* __restrict__ csr_src,
                const int* __restrict__ beg, const int* __restrict__ cur,
                float* __restrict__ h2) {
    int n  = blockIdx.x * 32 + (threadIdx.x >> 3);
    int c4 = threadIdx.x & 7;
    if (n >= N_NODES || c4 >= 5) return;
    int b = beg[n], end = cur[n];
    float4 acc = make_float4(0.f, 0.f, 0.f, 0.f);
    int j = b;
    for (; j + 1 < end; j += 2) {
        int s0 = csr_src[j], s1 = csr_src[j + 1];
        float4 v0 = *reinterpret_cast<const float4*>(N2 + (size_t)s0 * 20 + c4 * 4);
        float4 v1 = *reinterpret_cast<const float4*>(N2 + (size_t)s1 * 20 + c4 * 4);
        acc.x += v0.x + v1.x; acc.y += v0.y + v1.y;
        acc.z += v0.z + v1.z; acc.w += v0.w + v1.w;
    }
    if (j < end) {
        int s = csr_src[j];
        float4 v = *reinterpret_cast<const float4*>(N2 + (size_t)s * 20 + c4 * 4);
        acc.x += v.x; acc.y += v.y; acc.z += v.z; acc.w += v.w;
    }
    float inv = 1.0f / (float)max(end - b, 1);
    float4 s  = *reinterpret_cast<const float4*>(S2 + (size_t)n * 20 + c4 * 4);
    float4 bb = *reinterpret_cast<const float4*>(b2 + c4 * 4);
    float4 h;
    h.x = fmaxf(fmaf(acc.x, inv, s.x) + bb.x, 0.f);
    h.y = fmaxf(fmaf(acc.y, inv, s.y) + bb.y, 0.f);
    h.z = fmaxf(fmaf(acc.z, inv, s.z) + bb.z, 0.f);
    h.w = fmaxf(fmaf(acc.w, inv, s.w) + bb.w, 0.f);
    *reinterpret_cast<float4*>(h2 + (size_t)n * 20 + c4 * 4) = h;
}

// ---------------------------------------------------------------------------
// pool: per-graph sums + counts of h2.  graph_ids sorted -> most waves
// uniform -> wave shfl-reduce, 20 atomics/wave.
__global__ __launch_bounds__(256)
void pool_kernel(const float* __restrict__ h2, const int* __restrict__ gids,
                 float* __restrict__ pool, float* __restrict__ cnt) {
    int n = blockIdx.x * 256 + threadIdx.x;
    float h[20];
    int g = -1;
    if (n < N_NODES) {
        g = gids[n];
#pragma unroll
        for (int q = 0; q < 5; ++q) {
            float4 v = *reinterpret_cast<const float4*>(h2 + (size_t)n * 20 + q * 4);
            h[q * 4 + 0] = v.x; h[q * 4 + 1] = v.y;
            h[q * 4 + 2] = v.z; h[q * 4 + 3] = v.w;
        }
    } else {
#pragma unroll
        for (int c = 0; c < 20; ++c) h[c] = 0.f;
    }
    unsigned long long act = __ballot(n < N_NODES);
    int gfirst = __shfl(g, 0);
    bool uniform = __all(g == gfirst);
    if (uniform) {
        if (gfirst >= 0) {
#pragma unroll
            for (int c = 0; c < 20; ++c)
                for (int off2 = 32; off2 > 0; off2 >>= 1)
                    h[c] += __shfl_down(h[c], off2);
            if ((threadIdx.x & 63) == 0) {
                for (int c = 0; c < 20; ++c) atomAddF(&pool[gfirst * 20 + c], h[c]);
                atomAddF(&cnt[gfirst], (float)__popcll(act));
            }
        }
    } else if (n < N_NODES) {
        for (int c = 0; c < 20; ++c) atomAddF(&pool[g * 20 + c], h[c]);
        atomAddF(&cnt[g], 1.0f);
    }
}

// ---------------------------------------------------------------------------
// head: hg = pool/cnt; out = relu(hg@fc1+b1)@fc2+b2.  One block, thread per graph.
__global__ __launch_bounds__(64)
void head(const float* __restrict__ pool, const float* __restrict__ cnt,
          const float* __restrict__ fc1w, const float* __restrict__ fc1b,
          const float* __restrict__ fc2w, const float* __restrict__ fc2b,
          float* __restrict__ out) {
    int g = threadIdx.x;
    if (g >= N_GRAPHS) return;
    float inv = 1.0f / fmaxf(cnt[g], 1.0f);
    float hg[20];
    for (int c = 0; c < 20; ++c) hg[c] = pool[g * 20 + c] * inv;
    float o = fc2b[0];
    for (int j = 0; j < 10; ++j) {
        float t = fc1b[j];
        for (int c = 0; c < 20; ++c) t = fmaf(hg[c], fc1w[c * 10 + j], t);
        o = fmaf(fmaxf(t, 0.f), fc2w[j], o);
    }
    out[g] = o;
}

// ---------------------------------------------------------------------------
extern "C" void kernel_launch(void* const* d_in, const int* in_sizes, int n_in,
                              void* d_out, int out_size, void* d_ws, size_t ws_size,
                              hipStream_t stream) {
    const float* feat   = (const float*)d_in[0];
    const float* Wself1 = (const float*)d_in[1];
    const float* Wneigh1= (const float*)d_in[2];
    const float* b1     = (const float*)d_in[3];
    const float* Wself2 = (const float*)d_in[4];
    const float* Wneigh2= (const float*)d_in[5];
    const float* b2     = (const float*)d_in[6];
    const float* fc1w   = (const float*)d_in[7];
    const float* fc1b   = (const float*)d_in[8];
    const float* fc2w   = (const float*)d_in[9];
    const float* fc2b   = (const float*)d_in[10];
    const int*   src    = (const int*)d_in[11];
    const int*   dst    = (const int*)d_in[12];
    const int*   gids   = (const int*)d_in[13];
    float* ws = (float*)d_ws;

    // workspace layout (floats); regions recycled across phases
    float* S1 = ws;                        // 10,000,000 (dead after aggregate1)
    float* N1 = ws + 10000000;             // 10,000,000 (dead after aggregate1)
    float* h1 = ws + 20000000;             // 10,000,000
    float* S2 = N1;                        //  2,000,000
    float* N2 = N1 + 2000000;              //  2,000,000
    float* h2 = S1;                        //  2,000,000
    int*   deg  = (int*)(ws + 30000000);   //    100,000
    float* pool = ws + 30100000;           //      1,280
    float* cnt  = ws + 30101280;           //         64
    int*   ctr  = (int*)(ws + 30101344);   //          1 (range-alloc counter)
    int*   beg  = (int*)(ws + 30101360);   //    100,000 (CSR range starts)
    int*   cur  = (int*)(ws + 30201360);   //    100,000 (fill cursors -> range ends)
    int*   csr  = (int*)(ws + 30301360);   //    600,000 (CSR src indices)
    // total: 30,901,360 floats = ~117.9 MiB

    // zero deg + pool + cnt + ctr in one shot (contiguous region)
    hipMemsetAsync(deg, 0, (100000 + 1280 + 64 + 16) * sizeof(float), stream);

    deg_count<<<(N_EDGES + 255) / 256, 256, 0, stream>>>(dst, deg);
    alloc_ranges<<<(N_NODES + 255) / 256, 256, 0, stream>>>(deg, beg, cur, ctr);
    csr_fill<<<(N_EDGES + 255) / 256, 256, 0, stream>>>(src, dst, cur, csr);

    gemm1<<<N_NODES / 40, 256, 0, stream>>>(feat, Wself1, Wneigh1, S1, N1);

    aggregate1<<<(N_NODES + 7) / 8, 256, 0, stream>>>(N1, S1, b1, csr, beg, cur, h1);

    gemm2<<<(N_NODES + 63) / 64, 256, 0, stream>>>(h1, Wself2, Wneigh2, S2, N2);

    aggregate2<<<(N_NODES + 31) / 32, 256, 0, stream>>>(N2, S2, b2, csr, beg, cur, h2);

    pool_kernel<<<(N_NODES + 255) / 256, 256, 0, stream>>>(h2, gids, pool, cnt);

    head<<<1, 64, 0, stream>>>(pool, cnt, fc1w, fc1b, fc2w, fc2b, (float*)d_out);
}